// Round 4
// baseline (251.640 us; speedup 1.0000x reference)
//
#include <hip/hip_runtime.h>
#include <hip/hip_fp16.h>
#include <math.h>

#define N_NODES 50000
#define N_EDGES 800000
#define BIGV 1000000000.0f
#define NBLK_GEMM 3125  // 50000 / 16 nodes per block
#define CHUNK 4096      // edges per chunk in pass A
#define NBLK_A 196      // ceil(800000/4096)
#define NBUCKET 196     // dst>>8 in [0,195]

typedef _Float16 half8 __attribute__((ext_vector_type(8)));
typedef float floatx4 __attribute__((ext_vector_type(4)));

__device__ __forceinline__ float clampinf(float x) { return isinf(x) ? BIGV : x; }

// lgkm-only workgroup barrier: leaves global stores in flight.
__device__ __forceinline__ void barrier_lgkm_only() {
    __builtin_amdgcn_sched_barrier(0);
    asm volatile("s_waitcnt lgkmcnt(0)" ::: "memory");
    __builtin_amdgcn_s_barrier();
    __builtin_amdgcn_sched_barrier(0);
}

// ---------------------------------------------------------------------------
// k_prep: W pre-cast (fp16 W^T, 32 KB) + bns zero + PASS-A bucket histogram.
// R3 post-mortem: 3 rounds proved the 800K global RMW atomics are a flat
// ~20 G/s service wall (~35-40us) regardless of issue order / line sharding /
// coherence scope. Fix: eliminate them — group edges by dst with a two-pass
// bucket counting sort that uses ONLY LDS atomics.
// Pass A histogram: per 4096-edge chunk, LDS hist of dst>>8 (196 buckets)
// -> counts[chunk][bucket] (154 KB).
// ---------------------------------------------------------------------------
__global__ __launch_bounds__(256) void k_prep(const float* __restrict__ W,
                                              __half* __restrict__ wt,
                                              float* __restrict__ bns,
                                              const int* __restrict__ dst,
                                              int* __restrict__ counts)
{
    __shared__ int hist[NBUCKET];
    const int t = threadIdx.x;
    const int idx = blockIdx.x * 256 + t;      // grid 196*256 = 50176
    if (idx < 16384) {
        int n = idx >> 7, k = idx & 127;
        wt[idx] = __float2half(W[k * 128 + n]);
    }
    if (idx < 256) bns[idx] = 0.f;
    if (t < NBUCKET) hist[t] = 0;
    __syncthreads();
    const int base = blockIdx.x * CHUNK;
    for (int i = t; i < CHUNK; i += 256) {
        int e = base + i;
        if (e < N_EDGES) atomicAdd(&hist[dst[e] >> 8], 1);   // LDS atomic
    }
    __syncthreads();
    if (t < NBUCKET) counts[blockIdx.x * NBUCKET + t] = hist[t];
}

// ---------------------------------------------------------------------------
// K1: z = h @ W + b via MFMA f16 (fp32 accum), fp16 z out, fused per-node
// scores s=z.w_src / t=z.w_dst. PURE now — no histogram, no atomics.
// ---------------------------------------------------------------------------
__global__ __launch_bounds__(256) void k_gemm(
    const float* __restrict__ h, const __half* __restrict__ wt,
    const float* __restrict__ bias, const float* __restrict__ attn_w,
    __half* __restrict__ zh, float* __restrict__ sv, float* __restrict__ tv)
{
    __shared__ _Float16 hA[16][136];
    __shared__ float spart[4][16], tpart[4][16];

    const int tid = threadIdx.x;
    const int lane = tid & 63;
    const int wv = tid >> 6;          // wave 0..3
    const int l16 = lane & 15;
    const int oct = lane >> 4;
    const int n0 = wv << 5;           // this wave's 32-col strip
    const int node0 = blockIdx.x << 4;

    // stage h tile as fp16 (512 float4; 32 float4 per row)
    {
        const float4* h4 = (const float4*)(h + (size_t)node0 * 128);
        for (int i = tid; i < 512; i += 256) {
            int r = i >> 5, c4 = i & 31;
            float4 v = h4[i];
            union { __half2 h2[2]; uint2 u; } pk;
            pk.h2[0] = __floats2half2_rn(v.x, v.y);
            pk.h2[1] = __floats2half2_rn(v.z, v.w);
            *(uint2*)&hA[r][c4 << 2] = pk.u;
        }
    }

    // B-fragments in registers
    half8 bfrag[4][2];
    #pragma unroll
    for (int kk = 0; kk < 4; ++kk)
        #pragma unroll
        for (int t = 0; t < 2; ++t)
            bfrag[kk][t] = *(const half8*)(wt + (size_t)(n0 + t * 16 + l16) * 128
                                              + kk * 32 + oct * 8);

    const float bv0 = bias[n0 + l16],         bv1 = bias[n0 + 16 + l16];
    const float ws0 = attn_w[n0 + l16],       ws1 = attn_w[n0 + 16 + l16];
    const float wd0 = attn_w[128 + n0 + l16], wd1 = attn_w[128 + n0 + 16 + l16];

    barrier_lgkm_only();   // staging visible; global loads stay in flight

    floatx4 acc0 = {0.f, 0.f, 0.f, 0.f};
    floatx4 acc1 = {0.f, 0.f, 0.f, 0.f};
    #pragma unroll
    for (int kk = 0; kk < 4; ++kk) {
        half8 a = *(const half8*)&hA[l16][(kk << 5) + (oct << 3)];
        acc0 = __builtin_amdgcn_mfma_f32_16x16x32_f16(a, bfrag[kk][0], acc0, 0, 0, 0);
        acc1 = __builtin_amdgcn_mfma_f32_16x16x32_f16(a, bfrag[kk][1], acc1, 0, 0, 0);
    }

    float s_acc[4], t_acc[4];
    #pragma unroll
    for (int r = 0; r < 4; ++r) {
        float z0 = clampinf(acc0[r] + bv0);
        float z1 = clampinf(acc1[r] + bv1);
        const int row = (oct << 2) + r;
        zh[(size_t)(node0 + row) * 128 + n0 + l16]      = __float2half(z0);
        zh[(size_t)(node0 + row) * 128 + n0 + 16 + l16] = __float2half(z1);
        s_acc[r] = z0 * ws0 + z1 * ws1;
        t_acc[r] = z0 * wd0 + z1 * wd1;
    }
    #pragma unroll
    for (int r = 0; r < 4; ++r) {
        #pragma unroll
        for (int o = 1; o < 16; o <<= 1) {
            s_acc[r] += __shfl_xor(s_acc[r], o);
            t_acc[r] += __shfl_xor(t_acc[r], o);
        }
    }
    if (l16 == 0) {
        #pragma unroll
        for (int r = 0; r < 4; ++r) {
            spart[wv][(oct << 2) + r] = s_acc[r];
            tpart[wv][(oct << 2) + r] = t_acc[r];
        }
    }
    barrier_lgkm_only();   // spart/tpart visible; zh stores stay in flight
    if (tid < 16) {
        sv[node0 + tid] = spart[0][tid] + spart[1][tid] + spart[2][tid] + spart[3][tid];
        tv[node0 + tid] = tpart[0][tid] + tpart[1][tid] + tpart[2][tid] + tpart[3][tid];
    }
}

// ---------------------------------------------------------------------------
// PASS A scatter: each block redundantly scans the counts table (154 KB,
// L2-hit; coalesced across threads) to get its exclusive per-bucket base,
// then scatters edge ids into bucket-grouped tmp[] via LDS cursors.
// Block 0 also publishes the global bucket bases (bbase_g[197]).
// No ordering requirement within a bucket — softmax is permutation-invariant.
// ---------------------------------------------------------------------------
__global__ __launch_bounds__(256) void k_scatterA(const int* __restrict__ dst,
                                                  const int* __restrict__ counts,
                                                  int* __restrict__ tmp,
                                                  int* __restrict__ bbase_g)
{
    __shared__ int cur[NBUCKET];
    __shared__ int stot[256];
    const int t = threadIdx.x;
    const int self = blockIdx.x;
    int pre = 0, tot = 0;
    if (t < NBUCKET) {
        for (int b = 0; b < NBLK_A; ++b) {
            int c = counts[b * NBUCKET + t];   // coalesced across t
            if (b < self) pre += c;
            tot += c;
        }
    }
    stot[t] = (t < NBUCKET) ? tot : 0;
    __syncthreads();
    for (int off = 1; off < 256; off <<= 1) {   // inclusive scan
        int u = (t >= off) ? stot[t - off] : 0;
        __syncthreads();
        stot[t] += u;
        __syncthreads();
    }
    if (t < NBUCKET) {
        const int bb = stot[t] - tot;           // exclusive: bucket base
        cur[t] = bb + pre;                      // this block's slice start
        if (self == 0) bbase_g[t] = bb;
    }
    if (self == 0 && t == 0) bbase_g[NBUCKET] = N_EDGES;
    __syncthreads();
    const int base = self * CHUNK;
    for (int i = t; i < CHUNK; i += 256) {
        int e = base + i;
        if (e < N_EDGES) {
            int pos = atomicAdd(&cur[dst[e] >> 8], 1);   // LDS atomic
            tmp[pos] = e;
        }
    }
}

// ---------------------------------------------------------------------------
// PASS B: one block per bucket (~4082 edges, 256 dst values). LDS 256-bin
// histogram -> LDS scan -> writes colptr directly, then places each edge's
// FINAL record (score + leaky-relu fused — replaces old k_scatter) via
// ds_add_rtn cursors. recs writes land in a ~64 KB contiguous region.
// ---------------------------------------------------------------------------
__global__ __launch_bounds__(256) void k_binB(
    const int* __restrict__ tmp, const int* __restrict__ bbase_g,
    const int* __restrict__ dst, const int* __restrict__ src,
    const float* __restrict__ sigma,
    const float* __restrict__ sv, const float* __restrict__ tv,
    const float* __restrict__ attn_b,
    int* __restrict__ colptr, float4* __restrict__ recs)
{
    __shared__ int hist[256];
    __shared__ int scn[256];
    __shared__ int cur[256];
    const int t = threadIdx.x;
    const int b = blockIdx.x;
    const int s0 = bbase_g[b];
    const int n = bbase_g[b + 1] - s0;
    hist[t] = 0;
    __syncthreads();
    for (int i = t; i < n; i += 256) {
        int e = tmp[s0 + i];
        atomicAdd(&hist[dst[e] & 255], 1);      // LDS atomic
    }
    __syncthreads();
    scn[t] = hist[t];
    __syncthreads();
    for (int off = 1; off < 256; off <<= 1) {   // inclusive scan
        int u = (t >= off) ? scn[t - off] : 0;
        __syncthreads();
        scn[t] += u;
        __syncthreads();
    }
    const int excl = scn[t] - hist[t];
    cur[t] = s0 + excl;
    const int node = (b << 8) + t;
    if (node < N_NODES) colptr[node] = s0 + excl;
    if (b == 0 && t == 0) colptr[N_NODES] = N_EDGES;
    __syncthreads();
    const float ab = attn_b[0];
    for (int i = t; i < n; i += 256) {
        int e = tmp[s0 + i];
        int d = dst[e];
        int pos = atomicAdd(&cur[d & 255], 1);  // LDS atomic, final slot
        int s = src[e];
        float a = sv[s] + tv[d] + ab;
        a = clampinf(a);
        float ev = a > 0.f ? a : 0.01f * a;     // leaky relu
        float4 rec;
        rec.x = __int_as_float(s);
        rec.y = sigma[e];
        rec.z = ev;
        rec.w = 0.f;
        recs[pos] = rec;
    }
}

// ---------------------------------------------------------------------------
// K6: per-node softmax + weighted aggregate. One 64-lane wave per node.
// ---------------------------------------------------------------------------
__global__ __launch_bounds__(256) void k_agg(
    const int* __restrict__ colptr, const float4* __restrict__ recs,
    const __half* __restrict__ zh, float* __restrict__ out)
{
    const int lane = threadIdx.x & 63;
    const int node = blockIdx.x * 4 + (threadIdx.x >> 6);
    if (node >= N_NODES) return;
    const int base = colptr[node];
    const int deg = colptr[node + 1] - base;

    const int grp = lane >> 4;   // 0..3: which edge of the 4 in flight
    const int l16 = lane & 15;   // feature octet within the row
    float acc[8] = {0.f, 0.f, 0.f, 0.f, 0.f, 0.f, 0.f, 0.f};

    if (deg > 0) {
        if (deg <= 64) {
            // ---- fast path: everything in registers ----
            int sidx = 0; float sig = 0.f, e = -INFINITY;
            if (lane < deg) {
                float4 r = recs[base + lane];
                sidx = __float_as_int(r.x); sig = r.y; e = r.z;
            }
            float m = e;
            for (int o = 32; o; o >>= 1) m = fmaxf(m, __shfl_xor(m, o));
            float p = (lane < deg) ? __expf(e - m) : 0.f;
            float dn = p, bs = sig;
            for (int o = 32; o; o >>= 1) {
                dn += __shfl_xor(dn, o);
                bs += __shfl_xor(bs, o);
            }
            const float coef = p * sig * (1.0f / dn) / (bs + 1e-6f);
            for (int c = 0; c < deg; c += 4) {
                const int j = c + grp;                 // j <= 63 always
                const int js = (j < deg) ? j : 0;      // clamp source index
                float cf = __shfl(coef, js);           // uniform: all lanes
                int sj = __shfl(sidx, js);
                if (j < deg) {
                    uint4 raw = *(const uint4*)(zh + ((size_t)sj << 7) + (l16 << 3));
                    const __half2* hp = (const __half2*)&raw;
                    #pragma unroll
                    for (int k = 0; k < 4; ++k) {
                        float2 f = __half22float2(hp[k]);
                        acc[2*k]   = fmaf(cf, f.x, acc[2*k]);
                        acc[2*k+1] = fmaf(cf, f.y, acc[2*k+1]);
                    }
                }
            }
        } else {
            // ---- generic path (deg > 64, rare) ----
            float m = -INFINITY;
            for (int i = lane; i < deg; i += 64) m = fmaxf(m, recs[base + i].z);
            for (int o = 32; o; o >>= 1) m = fmaxf(m, __shfl_xor(m, o));
            float dn = 0.f, bs = 0.f;
            for (int i = lane; i < deg; i += 64) {
                float4 r = recs[base + i];
                dn += __expf(r.z - m); bs += r.y;
            }
            for (int o = 32; o; o >>= 1) {
                dn += __shfl_xor(dn, o);
                bs += __shfl_xor(bs, o);
            }
            const float scale = (1.0f / dn) / (bs + 1e-6f);
            for (int c = 0; c < deg; c += 64) {
                int i = c + lane;
                int sidx = 0; float coef = 0.f;
                if (i < deg) {
                    float4 r = recs[base + i];
                    sidx = __float_as_int(r.x);
                    coef = __expf(r.z - m) * r.y * scale;
                }
                const int cnt2 = min(64, deg - c);
                for (int j = 0; j < cnt2; j += 4) {
                    const int jj = j + grp;            // jj <= 63 always
                    const int js = (jj < cnt2) ? jj : 0;
                    float cf = __shfl(coef, js);       // uniform: all lanes
                    int sj = __shfl(sidx, js);
                    if (jj < cnt2) {
                        uint4 raw = *(const uint4*)(zh + ((size_t)sj << 7) + (l16 << 3));
                        const __half2* hp = (const __half2*)&raw;
                        #pragma unroll
                        for (int k = 0; k < 4; ++k) {
                            float2 f = __half22float2(hp[k]);
                            acc[2*k]   = fmaf(cf, f.x, acc[2*k]);
                            acc[2*k+1] = fmaf(cf, f.y, acc[2*k+1]);
                        }
                    }
                }
            }
        }
    }
    // combine the 4 groups
    #pragma unroll
    for (int k = 0; k < 8; ++k) {
        acc[k] += __shfl_xor(acc[k], 16);
        acc[k] += __shfl_xor(acc[k], 32);
    }
    if (grp == 0) {
        float4 o0, o1;
        o0.x = clampinf(acc[0]); o0.y = clampinf(acc[1]);
        o0.z = clampinf(acc[2]); o0.w = clampinf(acc[3]);
        o1.x = clampinf(acc[4]); o1.y = clampinf(acc[5]);
        o1.z = clampinf(acc[6]); o1.w = clampinf(acc[7]);
        float4* op = (float4*)(out + (size_t)node * 128 + (l16 << 3));
        op[0] = o0; op[1] = o1;
    }
}

// ---------------------------------------------------------------------------
// BatchNorm stats: float4-vectorized.
// ---------------------------------------------------------------------------
__global__ __launch_bounds__(256) void k_bnstats(const float* __restrict__ hnew,
                                                 float* __restrict__ sums)
{
    const int tid = threadIdx.x;
    const int f4 = (tid & 31) << 2;      // feature base (0,4,..124)
    const int rgrp = tid >> 5;           // 0..7
    float4 s = {0.f, 0.f, 0.f, 0.f}, q = {0.f, 0.f, 0.f, 0.f};
    for (int node = blockIdx.x * 8 + rgrp; node < N_NODES; node += 256 * 8) {
        float4 v = *(const float4*)(hnew + (size_t)node * 128 + f4);
        s.x += v.x; s.y += v.y; s.z += v.z; s.w += v.w;
        q.x += v.x * v.x; q.y += v.y * v.y; q.z += v.z * v.z; q.w += v.w * v.w;
    }
    __shared__ float4 ls[256], lq[256];
    ls[tid] = s; lq[tid] = q;
    __syncthreads();
    for (int off = 128; off >= 32; off >>= 1) {
        if (tid < off) {
            float4 a = ls[tid + off], b = lq[tid + off];
            ls[tid].x += a.x; ls[tid].y += a.y; ls[tid].z += a.z; ls[tid].w += a.w;
            lq[tid].x += b.x; lq[tid].y += b.y; lq[tid].z += b.z; lq[tid].w += b.w;
        }
        __syncthreads();
    }
    if (tid < 32) {
        float4 fs = ls[tid], fq = lq[tid];
        atomicAdd(&sums[f4 + 0], fs.x);
        atomicAdd(&sums[f4 + 1], fs.y);
        atomicAdd(&sums[f4 + 2], fs.z);
        atomicAdd(&sums[f4 + 3], fs.w);
        atomicAdd(&sums[128 + f4 + 0], fq.x);
        atomicAdd(&sums[128 + f4 + 1], fq.y);
        atomicAdd(&sums[128 + f4 + 2], fq.z);
        atomicAdd(&sums[128 + f4 + 3], fq.w);
    }
}

// ---------------------------------------------------------------------------
// BN apply + ELU: float4-vectorized; per-feature scale/shift in LDS.
// ---------------------------------------------------------------------------
__global__ __launch_bounds__(256) void k_bnapply(float* __restrict__ io,
                                                 const float* __restrict__ sums,
                                                 const float* __restrict__ gamma,
                                                 const float* __restrict__ beta)
{
    __shared__ float sc[128], sh[128];
    const int tid = threadIdx.x;
    if (tid < 128) {
        const float invn = 1.0f / (float)N_NODES;
        float mu = sums[tid] * invn;
        float var = fmaxf(sums[128 + tid] * invn - mu * mu, 0.f);
        float g = gamma[tid] * rsqrtf(var + 1e-5f);
        sc[tid] = g;
        sh[tid] = beta[tid] - mu * g;
    }
    __syncthreads();
    const size_t idx = (size_t)blockIdx.x * 256 + tid;   // float4 index
    const int f4 = ((int)idx & 31) << 2;
    float4 x = ((const float4*)io)[idx];
    float y0 = x.x * sc[f4 + 0] + sh[f4 + 0];
    float y1 = x.y * sc[f4 + 1] + sh[f4 + 1];
    float y2 = x.z * sc[f4 + 2] + sh[f4 + 2];
    float y3 = x.w * sc[f4 + 3] + sh[f4 + 3];
    float4 o;
    o.x = y0 > 0.f ? y0 : expm1f(y0);
    o.y = y1 > 0.f ? y1 : expm1f(y1);
    o.z = y2 > 0.f ? y2 : expm1f(y2);
    o.w = y3 > 0.f ? y3 : expm1f(y3);
    ((float4*)io)[idx] = o;
}

// ---------------------------------------------------------------------------
extern "C" void kernel_launch(void* const* d_in, const int* in_sizes, int n_in,
                              void* d_out, int out_size, void* d_ws, size_t ws_size,
                              hipStream_t stream)
{
    const float* h      = (const float*)d_in[0];
    const int*   src    = (const int*)  d_in[1];
    const int*   dst    = (const int*)  d_in[2];
    const float* sigma  = (const float*)d_in[3];
    const float* fc_w   = (const float*)d_in[4];
    const float* fc_b   = (const float*)d_in[5];
    const float* attn_w = (const float*)d_in[6];
    const float* attn_b = (const float*)d_in[7];
    const float* gamma  = (const float*)d_in[8];
    const float* beta   = (const float*)d_in[9];
    float* out = (float*)d_out;

    // workspace layout (~30 MB)
    float4* recs   = (float4*)d_ws;                         // 800000 x 16B
    __half* zh     = (__half*)(recs + N_EDGES);             // 50000*128 fp16
    float*  sv     = (float*)(zh + (size_t)N_NODES * 128);  // 50000
    float*  tv     = sv + N_NODES;                          // 50000
    float*  bns    = tv + N_NODES;                          // 256
    int*    colptr = (int*)(bns + 256);                     // 50001 (pad 50004)
    __half* wt     = (__half*)(colptr + 50004);             // 128*128 fp16 (W^T)
    int*    counts = (int*)(wt + 128 * 128);                // 196*196 (pad 38416)
    int*    bbase  = counts + 38416;                        // 197 (pad 256)
    int*    tmp    = bbase + 256;                           // 800000 edge ids

    k_prep     <<<NBLK_A, 256, 0, stream>>>(fc_w, wt, bns, dst, counts);
    k_scatterA <<<NBLK_A, 256, 0, stream>>>(dst, counts, tmp, bbase);
    k_gemm     <<<NBLK_GEMM, 256, 0, stream>>>(h, wt, fc_b, attn_w, zh, sv, tv);
    k_binB     <<<NBUCKET, 256, 0, stream>>>(tmp, bbase, dst, src, sigma,
                                             sv, tv, attn_b, colptr, recs);
    k_agg      <<<N_NODES / 4, 256, 0, stream>>>(colptr, recs, zh, out);
    k_bnstats  <<<256, 256, 0, stream>>>(out, bns);
    k_bnapply  <<<(N_NODES * 128) / (256 * 4), 256, 0, stream>>>(out, bns, gamma, beta);
}

// Round 5
// 235.550 us; speedup vs baseline: 1.0683x; 1.0683x over previous
//
#include <hip/hip_runtime.h>
#include <hip/hip_fp16.h>
#include <math.h>

#define N_NODES 50000
#define N_EDGES 800000
#define BIGV 1000000000.0f
#define NBLK_GEMM 3125  // 50000 / 16 nodes per block
#define CHUNK 4096      // edges per chunk (pass A granularity)
#define NCHUNK 196      // ceil(800000/4096)
#define NBUCKET 782     // dst>>6 in [0,781]
#define NB4 784         // bucket count padded to multiple of 4

typedef _Float16 half8 __attribute__((ext_vector_type(8)));
typedef float floatx4 __attribute__((ext_vector_type(4)));

__device__ __forceinline__ float clampinf(float x) { return isinf(x) ? BIGV : x; }

// lgkm-only workgroup barrier: leaves global stores in flight.
__device__ __forceinline__ void barrier_lgkm_only() {
    __builtin_amdgcn_sched_barrier(0);
    asm volatile("s_waitcnt lgkmcnt(0)" ::: "memory");
    __builtin_amdgcn_s_barrier();
    __builtin_amdgcn_sched_barrier(0);
}

// ---------------------------------------------------------------------------
// k_prep: W pre-cast (fp16 W^T) + bns zero + per-chunk bucket histogram.
// R4 post-mortem: pass-B random 4B gathers (52 MB FETCH) + 196-block
// occupancy were the regression. Buckets are now dst>>6 (782), and counts
// rows are [chunk][784] so later kernels read them as coalesced uint4.
// ---------------------------------------------------------------------------
__global__ __launch_bounds__(256) void k_prep(const float* __restrict__ W,
                                              __half* __restrict__ wt,
                                              float* __restrict__ bns,
                                              const int* __restrict__ dst,
                                              int* __restrict__ counts)
{
    __shared__ int hist[NB4];
    const int t = threadIdx.x;
    const int idx = blockIdx.x * 256 + t;
    if (idx < 16384) {
        int n = idx >> 7, k = idx & 127;
        wt[idx] = __float2half(W[k * 128 + n]);
    }
    if (idx < 256) bns[idx] = 0.f;
    for (int i = t; i < NB4; i += 256) hist[i] = 0;
    __syncthreads();
    const int base = blockIdx.x * CHUNK;
    for (int i = t; i < CHUNK; i += 256) {
        int e = base + i;
        if (e < N_EDGES) atomicAdd(&hist[dst[e] >> 6], 1);   // LDS atomic
    }
    __syncthreads();
    for (int i = t; i < NB4; i += 256) counts[blockIdx.x * NB4 + i] = hist[i];
}

// ---------------------------------------------------------------------------
// K1: z = h @ W + b via MFMA f16 (fp32 accum), fp16 z out, fused per-node
// scores s=z.w_src / t=z.w_dst. Pure — no histogram, no atomics.
// ---------------------------------------------------------------------------
__global__ __launch_bounds__(256) void k_gemm(
    const float* __restrict__ h, const __half* __restrict__ wt,
    const float* __restrict__ bias, const float* __restrict__ attn_w,
    __half* __restrict__ zh, float* __restrict__ sv, float* __restrict__ tv)
{
    __shared__ _Float16 hA[16][136];
    __shared__ float spart[4][16], tpart[4][16];

    const int tid = threadIdx.x;
    const int lane = tid & 63;
    const int wv = tid >> 6;          // wave 0..3
    const int l16 = lane & 15;
    const int oct = lane >> 4;
    const int n0 = wv << 5;           // this wave's 32-col strip
    const int node0 = blockIdx.x << 4;

    // stage h tile as fp16 (512 float4; 32 float4 per row)
    {
        const float4* h4 = (const float4*)(h + (size_t)node0 * 128);
        for (int i = tid; i < 512; i += 256) {
            int r = i >> 5, c4 = i & 31;
            float4 v = h4[i];
            union { __half2 h2[2]; uint2 u; } pk;
            pk.h2[0] = __floats2half2_rn(v.x, v.y);
            pk.h2[1] = __floats2half2_rn(v.z, v.w);
            *(uint2*)&hA[r][c4 << 2] = pk.u;
        }
    }

    // B-fragments in registers
    half8 bfrag[4][2];
    #pragma unroll
    for (int kk = 0; kk < 4; ++kk)
        #pragma unroll
        for (int t = 0; t < 2; ++t)
            bfrag[kk][t] = *(const half8*)(wt + (size_t)(n0 + t * 16 + l16) * 128
                                              + kk * 32 + oct * 8);

    const float bv0 = bias[n0 + l16],         bv1 = bias[n0 + 16 + l16];
    const float ws0 = attn_w[n0 + l16],       ws1 = attn_w[n0 + 16 + l16];
    const float wd0 = attn_w[128 + n0 + l16], wd1 = attn_w[128 + n0 + 16 + l16];

    barrier_lgkm_only();   // staging visible; global loads stay in flight

    floatx4 acc0 = {0.f, 0.f, 0.f, 0.f};
    floatx4 acc1 = {0.f, 0.f, 0.f, 0.f};
    #pragma unroll
    for (int kk = 0; kk < 4; ++kk) {
        half8 a = *(const half8*)&hA[l16][(kk << 5) + (oct << 3)];
        acc0 = __builtin_amdgcn_mfma_f32_16x16x32_f16(a, bfrag[kk][0], acc0, 0, 0, 0);
        acc1 = __builtin_amdgcn_mfma_f32_16x16x32_f16(a, bfrag[kk][1], acc1, 0, 0, 0);
    }

    float s_acc[4], t_acc[4];
    #pragma unroll
    for (int r = 0; r < 4; ++r) {
        float z0 = clampinf(acc0[r] + bv0);
        float z1 = clampinf(acc1[r] + bv1);
        const int row = (oct << 2) + r;
        zh[(size_t)(node0 + row) * 128 + n0 + l16]      = __float2half(z0);
        zh[(size_t)(node0 + row) * 128 + n0 + 16 + l16] = __float2half(z1);
        s_acc[r] = z0 * ws0 + z1 * ws1;
        t_acc[r] = z0 * wd0 + z1 * wd1;
    }
    #pragma unroll
    for (int r = 0; r < 4; ++r) {
        #pragma unroll
        for (int o = 1; o < 16; o <<= 1) {
            s_acc[r] += __shfl_xor(s_acc[r], o);
            t_acc[r] += __shfl_xor(t_acc[r], o);
        }
    }
    if (l16 == 0) {
        #pragma unroll
        for (int r = 0; r < 4; ++r) {
            spart[wv][(oct << 2) + r] = s_acc[r];
            tpart[wv][(oct << 2) + r] = t_acc[r];
        }
    }
    barrier_lgkm_only();   // spart/tpart visible; zh stores stay in flight
    if (tid < 16) {
        sv[node0 + tid] = spart[0][tid] + spart[1][tid] + spart[2][tid] + spart[3][tid];
        tv[node0 + tid] = tpart[0][tid] + tpart[1][tid] + tpart[2][tid] + tpart[3][tid];
    }
}

// ---------------------------------------------------------------------------
// PASS A (k_scat): per 4096-edge chunk, compute each edge's FINAL payload
// {src, sigma, leaky_relu(score), dst} while src/dst/sigma reads are
// COALESCED (e sequential; sv/tv are L2-resident gathers), and scatter the
// 16B record into its bucket slice via LDS cursors. Cursor setup: redundant
// prefix over the transposed counts table (196 uint4-coalesced rows, 614 KB,
// L2-hit) -> bucket bases (block-scan) + this chunk's within-bucket offset.
// Block 0 publishes bbase_g. No global atomics anywhere.
// ---------------------------------------------------------------------------
__global__ __launch_bounds__(256) void k_scat(
    const int* __restrict__ src, const int* __restrict__ dst,
    const float* __restrict__ sigma,
    const float* __restrict__ sv, const float* __restrict__ tv,
    const float* __restrict__ attn_b, const int* __restrict__ counts,
    float4* __restrict__ tmp, int* __restrict__ bbase_g)
{
    __shared__ int cur[NB4];
    __shared__ int tsc[256];
    const int t = threadIdx.x;
    const int self = blockIdx.x;

    uint4 pre = {0u, 0u, 0u, 0u}, tot = {0u, 0u, 0u, 0u};
    if (t < 196) {
        const uint4* c4 = (const uint4*)counts;   // rows of NB4/4 = 196 uint4
        for (int c = 0; c < NCHUNK; ++c) {
            uint4 v = c4[c * (NB4 / 4) + t];
            tot.x += v.x; tot.y += v.y; tot.z += v.z; tot.w += v.w;
            if (c < self) { pre.x += v.x; pre.y += v.y; pre.z += v.z; pre.w += v.w; }
        }
    }
    const int tsum = (t < 196) ? (int)(tot.x + tot.y + tot.z + tot.w) : 0;
    tsc[t] = tsum;
    __syncthreads();
    for (int off = 1; off < 256; off <<= 1) {    // inclusive block scan
        int u = (t >= off) ? tsc[t - off] : 0;
        __syncthreads();
        tsc[t] += u;
        __syncthreads();
    }
    if (t < 196) {
        const int v0 = tsc[t] - tsum;            // exclusive across threads
        const int v1 = v0 + (int)tot.x;
        const int v2 = v1 + (int)tot.y;
        const int v3 = v2 + (int)tot.z;
        cur[4*t+0] = v0 + (int)pre.x;
        cur[4*t+1] = v1 + (int)pre.y;
        cur[4*t+2] = v2 + (int)pre.z;
        cur[4*t+3] = v3 + (int)pre.w;
        if (self == 0) {                         // pre == 0 here: cur == bases
            bbase_g[4*t+0] = v0; bbase_g[4*t+1] = v1;
            bbase_g[4*t+2] = v2; bbase_g[4*t+3] = v3;
        }
    }
    if (self == 0 && t == 0) bbase_g[NBUCKET] = N_EDGES;
    __syncthreads();

    const float ab = attn_b[0];
    const int base = self * CHUNK;
    for (int i = t; i < CHUNK; i += 256) {
        int e = base + i;
        if (e < N_EDGES) {
            int s = src[e];
            int d = dst[e];
            float a = sv[s] + tv[d] + ab;
            a = clampinf(a);
            float ev = a > 0.f ? a : 0.01f * a;  // leaky relu
            int pos = atomicAdd(&cur[d >> 6], 1);  // LDS atomic
            float4 rec;
            rec.x = __int_as_float(s);
            rec.y = sigma[e];
            rec.z = ev;
            rec.w = __int_as_float(d);           // dst rides in .w for pass B
            tmp[pos] = rec;
        }
    }
}

// ---------------------------------------------------------------------------
// PASS B (k_binB): one block per bucket (~1023 edges, 64 dst values).
// Everything it reads is CONTIGUOUS (records carried from pass A). LDS
// 64-bin hist -> wave-shfl scan -> colptr, then final placement via LDS
// cursors; output writes land in a contiguous ~16 KB window.
// ---------------------------------------------------------------------------
__global__ __launch_bounds__(256) void k_binB(const float4* __restrict__ tmp,
                                              const int* __restrict__ bbase_g,
                                              int* __restrict__ colptr,
                                              float4* __restrict__ recs)
{
    __shared__ int hist[64];
    __shared__ int cur[64];
    const int t = threadIdx.x;
    const int b = blockIdx.x;
    const int s0 = bbase_g[b];
    const int n = bbase_g[b + 1] - s0;
    if (t < 64) hist[t] = 0;
    __syncthreads();
    const float* tw = (const float*)tmp;
    for (int i = t; i < n; i += 256) {
        int d = __float_as_int(tw[4 * (size_t)(s0 + i) + 3]);
        atomicAdd(&hist[d & 63], 1);             // LDS atomic
    }
    __syncthreads();
    if (t < 64) {                                // wave 0 only: shfl scan
        const int hv = hist[t];
        int x = hv;
        #pragma unroll
        for (int o = 1; o < 64; o <<= 1) {
            int u = __shfl_up(x, o);
            if (t >= o) x += u;
        }
        const int excl = x - hv;
        cur[t] = s0 + excl;
        const int node = (b << 6) + t;
        if (node < N_NODES) colptr[node] = s0 + excl;
    }
    if (b == 0 && t == 0) colptr[N_NODES] = N_EDGES;
    __syncthreads();
    for (int i = t; i < n; i += 256) {
        float4 rec = tmp[s0 + i];
        int d = __float_as_int(rec.w);
        int pos = atomicAdd(&cur[d & 63], 1);    // LDS atomic, final slot
        rec.w = 0.f;
        recs[pos] = rec;
    }
}

// ---------------------------------------------------------------------------
// K6: per-node softmax + weighted aggregate. One 64-lane wave per node.
// ---------------------------------------------------------------------------
__global__ __launch_bounds__(256) void k_agg(
    const int* __restrict__ colptr, const float4* __restrict__ recs,
    const __half* __restrict__ zh, float* __restrict__ out)
{
    const int lane = threadIdx.x & 63;
    const int node = blockIdx.x * 4 + (threadIdx.x >> 6);
    if (node >= N_NODES) return;
    const int base = colptr[node];
    const int deg = colptr[node + 1] - base;

    const int grp = lane >> 4;   // 0..3: which edge of the 4 in flight
    const int l16 = lane & 15;   // feature octet within the row
    float acc[8] = {0.f, 0.f, 0.f, 0.f, 0.f, 0.f, 0.f, 0.f};

    if (deg > 0) {
        if (deg <= 64) {
            // ---- fast path: everything in registers ----
            int sidx = 0; float sig = 0.f, e = -INFINITY;
            if (lane < deg) {
                float4 r = recs[base + lane];
                sidx = __float_as_int(r.x); sig = r.y; e = r.z;
            }
            float m = e;
            for (int o = 32; o; o >>= 1) m = fmaxf(m, __shfl_xor(m, o));
            float p = (lane < deg) ? __expf(e - m) : 0.f;
            float dn = p, bs = sig;
            for (int o = 32; o; o >>= 1) {
                dn += __shfl_xor(dn, o);
                bs += __shfl_xor(bs, o);
            }
            const float coef = p * sig * (1.0f / dn) / (bs + 1e-6f);
            for (int c = 0; c < deg; c += 4) {
                const int j = c + grp;                 // j <= 63 always
                const int js = (j < deg) ? j : 0;      // clamp source index
                float cf = __shfl(coef, js);           // uniform: all lanes
                int sj = __shfl(sidx, js);
                if (j < deg) {
                    uint4 raw = *(const uint4*)(zh + ((size_t)sj << 7) + (l16 << 3));
                    const __half2* hp = (const __half2*)&raw;
                    #pragma unroll
                    for (int k = 0; k < 4; ++k) {
                        float2 f = __half22float2(hp[k]);
                        acc[2*k]   = fmaf(cf, f.x, acc[2*k]);
                        acc[2*k+1] = fmaf(cf, f.y, acc[2*k+1]);
                    }
                }
            }
        } else {
            // ---- generic path (deg > 64, rare) ----
            float m = -INFINITY;
            for (int i = lane; i < deg; i += 64) m = fmaxf(m, recs[base + i].z);
            for (int o = 32; o; o >>= 1) m = fmaxf(m, __shfl_xor(m, o));
            float dn = 0.f, bs = 0.f;
            for (int i = lane; i < deg; i += 64) {
                float4 r = recs[base + i];
                dn += __expf(r.z - m); bs += r.y;
            }
            for (int o = 32; o; o >>= 1) {
                dn += __shfl_xor(dn, o);
                bs += __shfl_xor(bs, o);
            }
            const float scale = (1.0f / dn) / (bs + 1e-6f);
            for (int c = 0; c < deg; c += 64) {
                int i = c + lane;
                int sidx = 0; float coef = 0.f;
                if (i < deg) {
                    float4 r = recs[base + i];
                    sidx = __float_as_int(r.x);
                    coef = __expf(r.z - m) * r.y * scale;
                }
                const int cnt2 = min(64, deg - c);
                for (int j = 0; j < cnt2; j += 4) {
                    const int jj = j + grp;            // jj <= 63 always
                    const int js = (jj < cnt2) ? jj : 0;
                    float cf = __shfl(coef, js);       // uniform: all lanes
                    int sj = __shfl(sidx, js);
                    if (jj < cnt2) {
                        uint4 raw = *(const uint4*)(zh + ((size_t)sj << 7) + (l16 << 3));
                        const __half2* hp = (const __half2*)&raw;
                        #pragma unroll
                        for (int k = 0; k < 4; ++k) {
                            float2 f = __half22float2(hp[k]);
                            acc[2*k]   = fmaf(cf, f.x, acc[2*k]);
                            acc[2*k+1] = fmaf(cf, f.y, acc[2*k+1]);
                        }
                    }
                }
            }
        }
    }
    // combine the 4 groups
    #pragma unroll
    for (int k = 0; k < 8; ++k) {
        acc[k] += __shfl_xor(acc[k], 16);
        acc[k] += __shfl_xor(acc[k], 32);
    }
    if (grp == 0) {
        float4 o0, o1;
        o0.x = clampinf(acc[0]); o0.y = clampinf(acc[1]);
        o0.z = clampinf(acc[2]); o0.w = clampinf(acc[3]);
        o1.x = clampinf(acc[4]); o1.y = clampinf(acc[5]);
        o1.z = clampinf(acc[6]); o1.w = clampinf(acc[7]);
        float4* op = (float4*)(out + (size_t)node * 128 + (l16 << 3));
        op[0] = o0; op[1] = o1;
    }
}

// ---------------------------------------------------------------------------
// BatchNorm stats: float4-vectorized.
// ---------------------------------------------------------------------------
__global__ __launch_bounds__(256) void k_bnstats(const float* __restrict__ hnew,
                                                 float* __restrict__ sums)
{
    const int tid = threadIdx.x;
    const int f4 = (tid & 31) << 2;      // feature base (0,4,..124)
    const int rgrp = tid >> 5;           // 0..7
    float4 s = {0.f, 0.f, 0.f, 0.f}, q = {0.f, 0.f, 0.f, 0.f};
    for (int node = blockIdx.x * 8 + rgrp; node < N_NODES; node += 256 * 8) {
        float4 v = *(const float4*)(hnew + (size_t)node * 128 + f4);
        s.x += v.x; s.y += v.y; s.z += v.z; s.w += v.w;
        q.x += v.x * v.x; q.y += v.y * v.y; q.z += v.z * v.z; q.w += v.w * v.w;
    }
    __shared__ float4 ls[256], lq[256];
    ls[tid] = s; lq[tid] = q;
    __syncthreads();
    for (int off = 128; off >= 32; off >>= 1) {
        if (tid < off) {
            float4 a = ls[tid + off], b = lq[tid + off];
            ls[tid].x += a.x; ls[tid].y += a.y; ls[tid].z += a.z; ls[tid].w += a.w;
            lq[tid].x += b.x; lq[tid].y += b.y; lq[tid].z += b.z; lq[tid].w += b.w;
        }
        __syncthreads();
    }
    if (tid < 32) {
        float4 fs = ls[tid], fq = lq[tid];
        atomicAdd(&sums[f4 + 0], fs.x);
        atomicAdd(&sums[f4 + 1], fs.y);
        atomicAdd(&sums[f4 + 2], fs.z);
        atomicAdd(&sums[f4 + 3], fs.w);
        atomicAdd(&sums[128 + f4 + 0], fq.x);
        atomicAdd(&sums[128 + f4 + 1], fq.y);
        atomicAdd(&sums[128 + f4 + 2], fq.z);
        atomicAdd(&sums[128 + f4 + 3], fq.w);
    }
}

// ---------------------------------------------------------------------------
// BN apply + ELU: float4-vectorized; per-feature scale/shift in LDS.
// ---------------------------------------------------------------------------
__global__ __launch_bounds__(256) void k_bnapply(float* __restrict__ io,
                                                 const float* __restrict__ sums,
                                                 const float* __restrict__ gamma,
                                                 const float* __restrict__ beta)
{
    __shared__ float sc[128], sh[128];
    const int tid = threadIdx.x;
    if (tid < 128) {
        const float invn = 1.0f / (float)N_NODES;
        float mu = sums[tid] * invn;
        float var = fmaxf(sums[128 + tid] * invn - mu * mu, 0.f);
        float g = gamma[tid] * rsqrtf(var + 1e-5f);
        sc[tid] = g;
        sh[tid] = beta[tid] - mu * g;
    }
    __syncthreads();
    const size_t idx = (size_t)blockIdx.x * 256 + tid;   // float4 index
    const int f4 = ((int)idx & 31) << 2;
    float4 x = ((const float4*)io)[idx];
    float y0 = x.x * sc[f4 + 0] + sh[f4 + 0];
    float y1 = x.y * sc[f4 + 1] + sh[f4 + 1];
    float y2 = x.z * sc[f4 + 2] + sh[f4 + 2];
    float y3 = x.w * sc[f4 + 3] + sh[f4 + 3];
    float4 o;
    o.x = y0 > 0.f ? y0 : expm1f(y0);
    o.y = y1 > 0.f ? y1 : expm1f(y1);
    o.z = y2 > 0.f ? y2 : expm1f(y2);
    o.w = y3 > 0.f ? y3 : expm1f(y3);
    ((float4*)io)[idx] = o;
}

// ---------------------------------------------------------------------------
extern "C" void kernel_launch(void* const* d_in, const int* in_sizes, int n_in,
                              void* d_out, int out_size, void* d_ws, size_t ws_size,
                              hipStream_t stream)
{
    const float* h      = (const float*)d_in[0];
    const int*   src    = (const int*)  d_in[1];
    const int*   dst    = (const int*)  d_in[2];
    const float* sigma  = (const float*)d_in[3];
    const float* fc_w   = (const float*)d_in[4];
    const float* fc_b   = (const float*)d_in[5];
    const float* attn_w = (const float*)d_in[6];
    const float* attn_b = (const float*)d_in[7];
    const float* gamma  = (const float*)d_in[8];
    const float* beta   = (const float*)d_in[9];
    float* out = (float*)d_out;

    // workspace layout (~40 MB)
    float4* recs   = (float4*)d_ws;                         // 800000 x 16B
    float4* tmp    = recs + N_EDGES;                        // 800000 x 16B
    __half* zh     = (__half*)(tmp + N_EDGES);              // 50000*128 fp16
    float*  sv     = (float*)(zh + (size_t)N_NODES * 128);  // 50000
    float*  tv     = sv + N_NODES;                          // 50000
    float*  bns    = tv + N_NODES;                          // 256
    int*    colptr = (int*)(bns + 256);                     // 50001 (pad 50004)
    __half* wt     = (__half*)(colptr + 50004);             // 128*128 fp16 (W^T)
    int*    counts = (int*)(wt + 16384);                    // 196*784 ints
    int*    bbase  = counts + NCHUNK * NB4;                 // 783 (pad 784)

    k_prep    <<<NCHUNK, 256, 0, stream>>>(fc_w, wt, bns, dst, counts);
    k_gemm    <<<NBLK_GEMM, 256, 0, stream>>>(h, wt, fc_b, attn_w, zh, sv, tv);
    k_scat    <<<NCHUNK, 256, 0, stream>>>(src, dst, sigma, sv, tv, attn_b,
                                           counts, tmp, bbase);
    k_binB    <<<NBUCKET, 256, 0, stream>>>(tmp, bbase, colptr, recs);
    k_agg     <<<N_NODES / 4, 256, 0, stream>>>(colptr, recs, zh, out);
    k_bnstats <<<256, 256, 0, stream>>>(out, bns);
    k_bnapply <<<(N_NODES * 128) / (256 * 4), 256, 0, stream>>>(out, bns, gamma, beta);
}

// Round 6
// 225.416 us; speedup vs baseline: 1.1163x; 1.0450x over previous
//
#include <hip/hip_runtime.h>
#include <hip/hip_fp16.h>
#include <math.h>

#define N_NODES 50000
#define N_EDGES 800000
#define BIGV 1000000000.0f
#define NBLK_GEMM 3125  // 50000 / 16 nodes per block
#define CHUNK 1024      // edges per chunk (pass A granularity)
#define NCHUNK 782      // ceil(800000/1024)
#define NBUCKET 782     // dst>>6 in [0,781]
#define NB4 784         // bucket / chunk count padded to multiple of 4

typedef _Float16 half8 __attribute__((ext_vector_type(8)));
typedef float floatx4 __attribute__((ext_vector_type(4)));

__device__ __forceinline__ float clampinf(float x) { return isinf(x) ? BIGV : x; }

// lgkm-only workgroup barrier: leaves global stores in flight.
__device__ __forceinline__ void barrier_lgkm_only() {
    __builtin_amdgcn_sched_barrier(0);
    asm volatile("s_waitcnt lgkmcnt(0)" ::: "memory");
    __builtin_amdgcn_s_barrier();
    __builtin_amdgcn_sched_barrier(0);
}

// ---------------------------------------------------------------------------
// k_prep: W pre-cast (fp16 W^T) + bns zero + per-chunk bucket histogram.
// R5 post-mortem: k_scat's 53us was 196-block occupancy starvation + a
// serial 196-iteration redundant prefix. Chunks are now 1024 edges (782
// blocks, ~3/CU) and the prefix moved to a parallel wave-scan kernel (k_off).
// Histogram written TRANSPOSED: countsT[bucket][chunk] so k_off reads
// coalesced along the chunk axis.
// ---------------------------------------------------------------------------
__global__ __launch_bounds__(256) void k_prep(const float* __restrict__ W,
                                              __half* __restrict__ wt,
                                              float* __restrict__ bns,
                                              const int* __restrict__ dst,
                                              int* __restrict__ countsT)
{
    __shared__ int hist[NB4];
    const int t = threadIdx.x;
    const int idx = blockIdx.x * 256 + t;
    if (idx < 16384) {
        int n = idx >> 7, k = idx & 127;
        wt[idx] = __float2half(W[k * 128 + n]);
    }
    if (idx < 256) bns[idx] = 0.f;
    for (int i = t; i < NB4; i += 256) hist[i] = 0;
    __syncthreads();
    const int base = blockIdx.x * CHUNK;
    for (int i = t; i < CHUNK; i += 256) {
        int e = base + i;
        if (e < N_EDGES) atomicAdd(&hist[dst[e] >> 6], 1);   // LDS atomic
    }
    __syncthreads();
    for (int i = t; i < NB4; i += 256)
        countsT[i * NB4 + blockIdx.x] = hist[i];             // transposed store
}

// ---------------------------------------------------------------------------
// k_off: ONE WAVE PER BUCKET. Exclusive prefix over the 782 chunks of its
// bucket via 13-pass shfl_up wave-scan (coalesced reads of countsT row),
// writing cursC[chunk][bucket] (so k_scat reads its row coalesced) and
// btot[bucket]. Waves >= NBUCKET zero the btot padding (needed by the
// redundant bbase scan in k_scat).
// ---------------------------------------------------------------------------
__global__ __launch_bounds__(256) void k_off(const int* __restrict__ countsT,
                                             int* __restrict__ cursC,
                                             int* __restrict__ btot)
{
    const int wv = (blockIdx.x << 2) + (threadIdx.x >> 6);   // bucket id
    const int l = threadIdx.x & 63;
    if (wv >= NBUCKET) {
        if (l == 0 && wv < NB4) btot[wv] = 0;
        return;
    }
    const int* row = countsT + (size_t)wv * NB4;
    int carry = 0;
    #pragma unroll
    for (int p = 0; p < 13; ++p) {                           // 13*64 = 832 >= 782
        const int c = p * 64 + l;
        const int v = (c < NCHUNK) ? row[c] : 0;
        int x = v;                                           // inclusive wave scan
        #pragma unroll
        for (int o = 1; o < 64; o <<= 1) {
            int u = __shfl_up(x, o);
            if (l >= o) x += u;
        }
        if (c < NCHUNK) cursC[(size_t)c * NB4 + wv] = carry + x - v;
        carry += __shfl(x, 63);
    }
    if (l == 0) btot[wv] = carry;
}

// ---------------------------------------------------------------------------
// K1: z = h @ W + b via MFMA f16 (fp32 accum), fp16 z out, fused per-node
// scores s=z.w_src / t=z.w_dst. Pure — no histogram, no atomics.
// ---------------------------------------------------------------------------
__global__ __launch_bounds__(256) void k_gemm(
    const float* __restrict__ h, const __half* __restrict__ wt,
    const float* __restrict__ bias, const float* __restrict__ attn_w,
    __half* __restrict__ zh, float* __restrict__ sv, float* __restrict__ tv)
{
    __shared__ _Float16 hA[16][136];
    __shared__ float spart[4][16], tpart[4][16];

    const int tid = threadIdx.x;
    const int lane = tid & 63;
    const int wv = tid >> 6;          // wave 0..3
    const int l16 = lane & 15;
    const int oct = lane >> 4;
    const int n0 = wv << 5;           // this wave's 32-col strip
    const int node0 = blockIdx.x << 4;

    // stage h tile as fp16 (512 float4; 32 float4 per row)
    {
        const float4* h4 = (const float4*)(h + (size_t)node0 * 128);
        for (int i = tid; i < 512; i += 256) {
            int r = i >> 5, c4 = i & 31;
            float4 v = h4[i];
            union { __half2 h2[2]; uint2 u; } pk;
            pk.h2[0] = __floats2half2_rn(v.x, v.y);
            pk.h2[1] = __floats2half2_rn(v.z, v.w);
            *(uint2*)&hA[r][c4 << 2] = pk.u;
        }
    }

    // B-fragments in registers
    half8 bfrag[4][2];
    #pragma unroll
    for (int kk = 0; kk < 4; ++kk)
        #pragma unroll
        for (int t = 0; t < 2; ++t)
            bfrag[kk][t] = *(const half8*)(wt + (size_t)(n0 + t * 16 + l16) * 128
                                              + kk * 32 + oct * 8);

    const float bv0 = bias[n0 + l16],         bv1 = bias[n0 + 16 + l16];
    const float ws0 = attn_w[n0 + l16],       ws1 = attn_w[n0 + 16 + l16];
    const float wd0 = attn_w[128 + n0 + l16], wd1 = attn_w[128 + n0 + 16 + l16];

    barrier_lgkm_only();   // staging visible; global loads stay in flight

    floatx4 acc0 = {0.f, 0.f, 0.f, 0.f};
    floatx4 acc1 = {0.f, 0.f, 0.f, 0.f};
    #pragma unroll
    for (int kk = 0; kk < 4; ++kk) {
        half8 a = *(const half8*)&hA[l16][(kk << 5) + (oct << 3)];
        acc0 = __builtin_amdgcn_mfma_f32_16x16x32_f16(a, bfrag[kk][0], acc0, 0, 0, 0);
        acc1 = __builtin_amdgcn_mfma_f32_16x16x32_f16(a, bfrag[kk][1], acc1, 0, 0, 0);
    }

    float s_acc[4], t_acc[4];
    #pragma unroll
    for (int r = 0; r < 4; ++r) {
        float z0 = clampinf(acc0[r] + bv0);
        float z1 = clampinf(acc1[r] + bv1);
        const int row = (oct << 2) + r;
        zh[(size_t)(node0 + row) * 128 + n0 + l16]      = __float2half(z0);
        zh[(size_t)(node0 + row) * 128 + n0 + 16 + l16] = __float2half(z1);
        s_acc[r] = z0 * ws0 + z1 * ws1;
        t_acc[r] = z0 * wd0 + z1 * wd1;
    }
    #pragma unroll
    for (int r = 0; r < 4; ++r) {
        #pragma unroll
        for (int o = 1; o < 16; o <<= 1) {
            s_acc[r] += __shfl_xor(s_acc[r], o);
            t_acc[r] += __shfl_xor(t_acc[r], o);
        }
    }
    if (l16 == 0) {
        #pragma unroll
        for (int r = 0; r < 4; ++r) {
            spart[wv][(oct << 2) + r] = s_acc[r];
            tpart[wv][(oct << 2) + r] = t_acc[r];
        }
    }
    barrier_lgkm_only();   // spart/tpart visible; zh stores stay in flight
    if (tid < 16) {
        sv[node0 + tid] = spart[0][tid] + spart[1][tid] + spart[2][tid] + spart[3][tid];
        tv[node0 + tid] = tpart[0][tid] + tpart[1][tid] + tpart[2][tid] + tpart[3][tid];
    }
}

// ---------------------------------------------------------------------------
// PASS A (k_scat): per 1024-edge chunk. Cursor setup is now CHEAP: coalesced
// read of this chunk's cursC row + redundant LDS scan of btot (784 ints) for
// bucket bases. Then compute each edge's FINAL payload {src, sigma,
// leaky_relu(score), dst} with coalesced src/dst/sigma reads and scatter the
// 16B record into its bucket slice via LDS cursors. Block 0 publishes bbase.
// ---------------------------------------------------------------------------
__global__ __launch_bounds__(256) void k_scat(
    const int* __restrict__ src, const int* __restrict__ dst,
    const float* __restrict__ sigma,
    const float* __restrict__ sv, const float* __restrict__ tv,
    const float* __restrict__ attn_b,
    const int* __restrict__ cursC, const int* __restrict__ btot,
    float4* __restrict__ tmp, int* __restrict__ bbase_g)
{
    __shared__ int cur[NB4];
    __shared__ int bb[NB4];
    __shared__ int tsc[256];
    const int t = threadIdx.x;
    const int self = blockIdx.x;

    // this chunk's within-bucket offsets (coalesced row read)
    for (int i = t; i < NB4; i += 256) cur[i] = cursC[(size_t)self * NB4 + i];

    // redundant bucket-base scan over btot (padding zeroed by k_off)
    uint4 bt = {0u, 0u, 0u, 0u};
    int tsum = 0;
    if (t < 196) {
        bt = ((const uint4*)btot)[t];
        tsum = (int)(bt.x + bt.y + bt.z + bt.w);
    }
    tsc[t] = tsum;
    __syncthreads();
    for (int off = 1; off < 256; off <<= 1) {    // inclusive block scan
        int u = (t >= off) ? tsc[t - off] : 0;
        __syncthreads();
        tsc[t] += u;
        __syncthreads();
    }
    if (t < 196) {
        const int v0 = tsc[t] - tsum;            // exclusive
        bb[4*t+0] = v0;
        bb[4*t+1] = v0 + (int)bt.x;
        bb[4*t+2] = v0 + (int)bt.x + (int)bt.y;
        bb[4*t+3] = v0 + (int)bt.x + (int)bt.y + (int)bt.z;
    }
    __syncthreads();
    for (int i = t; i < NB4; i += 256) cur[i] += bb[i];
    if (self == 0)
        for (int i = t; i < NB4; i += 256) bbase_g[i] = bb[i];
    __syncthreads();

    const float ab = attn_b[0];
    const int base = self * CHUNK;
    for (int i = t; i < CHUNK; i += 256) {
        int e = base + i;
        if (e < N_EDGES) {
            int s = src[e];
            int d = dst[e];
            float a = sv[s] + tv[d] + ab;
            a = clampinf(a);
            float ev = a > 0.f ? a : 0.01f * a;  // leaky relu
            int pos = atomicAdd(&cur[d >> 6], 1);  // LDS atomic
            float4 rec;
            rec.x = __int_as_float(s);
            rec.y = sigma[e];
            rec.z = ev;
            rec.w = __int_as_float(d);           // dst rides in .w for pass B
            tmp[pos] = rec;
        }
    }
}

// ---------------------------------------------------------------------------
// PASS B (k_binB): one block per bucket (~1023 edges, 64 dst values).
// Everything it reads is CONTIGUOUS. LDS 64-bin hist -> wave-shfl scan ->
// colptr, then final placement via LDS cursors; contiguous output window.
// ---------------------------------------------------------------------------
__global__ __launch_bounds__(256) void k_binB(const float4* __restrict__ tmp,
                                              const int* __restrict__ bbase_g,
                                              int* __restrict__ colptr,
                                              float4* __restrict__ recs)
{
    __shared__ int hist[64];
    __shared__ int cur[64];
    const int t = threadIdx.x;
    const int b = blockIdx.x;
    const int s0 = bbase_g[b];
    const int n = ((b + 1 < NB4) ? bbase_g[b + 1] : N_EDGES) - s0;
    if (t < 64) hist[t] = 0;
    __syncthreads();
    const float* tw = (const float*)tmp;
    for (int i = t; i < n; i += 256) {
        int d = __float_as_int(tw[4 * (size_t)(s0 + i) + 3]);
        atomicAdd(&hist[d & 63], 1);             // LDS atomic
    }
    __syncthreads();
    if (t < 64) {                                // wave 0 only: shfl scan
        const int hv = hist[t];
        int x = hv;
        #pragma unroll
        for (int o = 1; o < 64; o <<= 1) {
            int u = __shfl_up(x, o);
            if (t >= o) x += u;
        }
        const int excl = x - hv;
        cur[t] = s0 + excl;
        const int node = (b << 6) + t;
        if (node < N_NODES) colptr[node] = s0 + excl;
    }
    if (b == 0 && t == 0) colptr[N_NODES] = N_EDGES;
    __syncthreads();
    for (int i = t; i < n; i += 256) {
        float4 rec = tmp[s0 + i];
        int d = __float_as_int(rec.w);
        int pos = atomicAdd(&cur[d & 63], 1);    // LDS atomic, final slot
        rec.w = 0.f;
        recs[pos] = rec;
    }
}

// ---------------------------------------------------------------------------
// K6: per-node softmax + weighted aggregate. One 64-lane wave per node.
// ---------------------------------------------------------------------------
__global__ __launch_bounds__(256) void k_agg(
    const int* __restrict__ colptr, const float4* __restrict__ recs,
    const __half* __restrict__ zh, float* __restrict__ out)
{
    const int lane = threadIdx.x & 63;
    const int node = blockIdx.x * 4 + (threadIdx.x >> 6);
    if (node >= N_NODES) return;
    const int base = colptr[node];
    const int deg = colptr[node + 1] - base;

    const int grp = lane >> 4;   // 0..3: which edge of the 4 in flight
    const int l16 = lane & 15;   // feature octet within the row
    float acc[8] = {0.f, 0.f, 0.f, 0.f, 0.f, 0.f, 0.f, 0.f};

    if (deg > 0) {
        if (deg <= 64) {
            // ---- fast path: everything in registers ----
            int sidx = 0; float sig = 0.f, e = -INFINITY;
            if (lane < deg) {
                float4 r = recs[base + lane];
                sidx = __float_as_int(r.x); sig = r.y; e = r.z;
            }
            float m = e;
            for (int o = 32; o; o >>= 1) m = fmaxf(m, __shfl_xor(m, o));
            float p = (lane < deg) ? __expf(e - m) : 0.f;
            float dn = p, bs = sig;
            for (int o = 32; o; o >>= 1) {
                dn += __shfl_xor(dn, o);
                bs += __shfl_xor(bs, o);
            }
            const float coef = p * sig * (1.0f / dn) / (bs + 1e-6f);
            for (int c = 0; c < deg; c += 4) {
                const int j = c + grp;                 // j <= 63 always
                const int js = (j < deg) ? j : 0;      // clamp source index
                float cf = __shfl(coef, js);           // uniform: all lanes
                int sj = __shfl(sidx, js);
                if (j < deg) {
                    uint4 raw = *(const uint4*)(zh + ((size_t)sj << 7) + (l16 << 3));
                    const __half2* hp = (const __half2*)&raw;
                    #pragma unroll
                    for (int k = 0; k < 4; ++k) {
                        float2 f = __half22float2(hp[k]);
                        acc[2*k]   = fmaf(cf, f.x, acc[2*k]);
                        acc[2*k+1] = fmaf(cf, f.y, acc[2*k+1]);
                    }
                }
            }
        } else {
            // ---- generic path (deg > 64, rare) ----
            float m = -INFINITY;
            for (int i = lane; i < deg; i += 64) m = fmaxf(m, recs[base + i].z);
            for (int o = 32; o; o >>= 1) m = fmaxf(m, __shfl_xor(m, o));
            float dn = 0.f, bs = 0.f;
            for (int i = lane; i < deg; i += 64) {
                float4 r = recs[base + i];
                dn += __expf(r.z - m); bs += r.y;
            }
            for (int o = 32; o; o >>= 1) {
                dn += __shfl_xor(dn, o);
                bs += __shfl_xor(bs, o);
            }
            const float scale = (1.0f / dn) / (bs + 1e-6f);
            for (int c = 0; c < deg; c += 64) {
                int i = c + lane;
                int sidx = 0; float coef = 0.f;
                if (i < deg) {
                    float4 r = recs[base + i];
                    sidx = __float_as_int(r.x);
                    coef = __expf(r.z - m) * r.y * scale;
                }
                const int cnt2 = min(64, deg - c);
                for (int j = 0; j < cnt2; j += 4) {
                    const int jj = j + grp;            // jj <= 63 always
                    const int js = (jj < cnt2) ? jj : 0;
                    float cf = __shfl(coef, js);       // uniform: all lanes
                    int sj = __shfl(sidx, js);
                    if (jj < cnt2) {
                        uint4 raw = *(const uint4*)(zh + ((size_t)sj << 7) + (l16 << 3));
                        const __half2* hp = (const __half2*)&raw;
                        #pragma unroll
                        for (int k = 0; k < 4; ++k) {
                            float2 f = __half22float2(hp[k]);
                            acc[2*k]   = fmaf(cf, f.x, acc[2*k]);
                            acc[2*k+1] = fmaf(cf, f.y, acc[2*k+1]);
                        }
                    }
                }
            }
        }
    }
    // combine the 4 groups
    #pragma unroll
    for (int k = 0; k < 8; ++k) {
        acc[k] += __shfl_xor(acc[k], 16);
        acc[k] += __shfl_xor(acc[k], 32);
    }
    if (grp == 0) {
        float4 o0, o1;
        o0.x = clampinf(acc[0]); o0.y = clampinf(acc[1]);
        o0.z = clampinf(acc[2]); o0.w = clampinf(acc[3]);
        o1.x = clampinf(acc[4]); o1.y = clampinf(acc[5]);
        o1.z = clampinf(acc[6]); o1.w = clampinf(acc[7]);
        float4* op = (float4*)(out + (size_t)node * 128 + (l16 << 3));
        op[0] = o0; op[1] = o1;
    }
}

// ---------------------------------------------------------------------------
// BatchNorm stats: float4-vectorized.
// ---------------------------------------------------------------------------
__global__ __launch_bounds__(256) void k_bnstats(const float* __restrict__ hnew,
                                                 float* __restrict__ sums)
{
    const int tid = threadIdx.x;
    const int f4 = (tid & 31) << 2;      // feature base (0,4,..124)
    const int rgrp = tid >> 5;           // 0..7
    float4 s = {0.f, 0.f, 0.f, 0.f}, q = {0.f, 0.f, 0.f, 0.f};
    for (int node = blockIdx.x * 8 + rgrp; node < N_NODES; node += 256 * 8) {
        float4 v = *(const float4*)(hnew + (size_t)node * 128 + f4);
        s.x += v.x; s.y += v.y; s.z += v.z; s.w += v.w;
        q.x += v.x * v.x; q.y += v.y * v.y; q.z += v.z * v.z; q.w += v.w * v.w;
    }
    __shared__ float4 ls[256], lq[256];
    ls[tid] = s; lq[tid] = q;
    __syncthreads();
    for (int off = 128; off >= 32; off >>= 1) {
        if (tid < off) {
            float4 a = ls[tid + off], b = lq[tid + off];
            ls[tid].x += a.x; ls[tid].y += a.y; ls[tid].z += a.z; ls[tid].w += a.w;
            lq[tid].x += b.x; lq[tid].y += b.y; lq[tid].z += b.z; lq[tid].w += b.w;
        }
        __syncthreads();
    }
    if (tid < 32) {
        float4 fs = ls[tid], fq = lq[tid];
        atomicAdd(&sums[f4 + 0], fs.x);
        atomicAdd(&sums[f4 + 1], fs.y);
        atomicAdd(&sums[f4 + 2], fs.z);
        atomicAdd(&sums[f4 + 3], fs.w);
        atomicAdd(&sums[128 + f4 + 0], fq.x);
        atomicAdd(&sums[128 + f4 + 1], fq.y);
        atomicAdd(&sums[128 + f4 + 2], fq.z);
        atomicAdd(&sums[128 + f4 + 3], fq.w);
    }
}

// ---------------------------------------------------------------------------
// BN apply + ELU: float4-vectorized; per-feature scale/shift in LDS.
// ---------------------------------------------------------------------------
__global__ __launch_bounds__(256) void k_bnapply(float* __restrict__ io,
                                                 const float* __restrict__ sums,
                                                 const float* __restrict__ gamma,
                                                 const float* __restrict__ beta)
{
    __shared__ float sc[128], sh[128];
    const int tid = threadIdx.x;
    if (tid < 128) {
        const float invn = 1.0f / (float)N_NODES;
        float mu = sums[tid] * invn;
        float var = fmaxf(sums[128 + tid] * invn - mu * mu, 0.f);
        float g = gamma[tid] * rsqrtf(var + 1e-5f);
        sc[tid] = g;
        sh[tid] = beta[tid] - mu * g;
    }
    __syncthreads();
    const size_t idx = (size_t)blockIdx.x * 256 + tid;   // float4 index
    const int f4 = ((int)idx & 31) << 2;
    float4 x = ((const float4*)io)[idx];
    float y0 = x.x * sc[f4 + 0] + sh[f4 + 0];
    float y1 = x.y * sc[f4 + 1] + sh[f4 + 1];
    float y2 = x.z * sc[f4 + 2] + sh[f4 + 2];
    float y3 = x.w * sc[f4 + 3] + sh[f4 + 3];
    float4 o;
    o.x = y0 > 0.f ? y0 : expm1f(y0);
    o.y = y1 > 0.f ? y1 : expm1f(y1);
    o.z = y2 > 0.f ? y2 : expm1f(y2);
    o.w = y3 > 0.f ? y3 : expm1f(y3);
    ((float4*)io)[idx] = o;
}

// ---------------------------------------------------------------------------
extern "C" void kernel_launch(void* const* d_in, const int* in_sizes, int n_in,
                              void* d_out, int out_size, void* d_ws, size_t ws_size,
                              hipStream_t stream)
{
    const float* h      = (const float*)d_in[0];
    const int*   src    = (const int*)  d_in[1];
    const int*   dst    = (const int*)  d_in[2];
    const float* sigma  = (const float*)d_in[3];
    const float* fc_w   = (const float*)d_in[4];
    const float* fc_b   = (const float*)d_in[5];
    const float* attn_w = (const float*)d_in[6];
    const float* attn_b = (const float*)d_in[7];
    const float* gamma  = (const float*)d_in[8];
    const float* beta   = (const float*)d_in[9];
    float* out = (float*)d_out;

    // workspace layout (~45 MB)
    float4* recs   = (float4*)d_ws;                         // 800000 x 16B
    float4* tmp    = recs + N_EDGES;                        // 800000 x 16B
    __half* zh     = (__half*)(tmp + N_EDGES);              // 50000*128 fp16
    float*  sv     = (float*)(zh + (size_t)N_NODES * 128);  // 50000
    float*  tv     = sv + N_NODES;                          // 50000
    float*  bns    = tv + N_NODES;                          // 256
    int*    colptr = (int*)(bns + 256);                     // 50001 (pad 50004)
    __half* wt     = (__half*)(colptr + 50004);             // 128*128 fp16 (W^T)
    int*    countsT= (int*)(wt + 16384);                    // 784*784
    int*    cursC  = countsT + NB4 * NB4;                   // 784*784
    int*    btot   = cursC + NB4 * NB4;                     // 784
    int*    bbase  = btot + NB4;                            // 784

    k_prep    <<<NCHUNK, 256, 0, stream>>>(fc_w, wt, bns, dst, countsT);
    k_off     <<<196, 256, 0, stream>>>(countsT, cursC, btot);
    k_gemm    <<<NBLK_GEMM, 256, 0, stream>>>(h, wt, fc_b, attn_w, zh, sv, tv);
    k_scat    <<<NCHUNK, 256, 0, stream>>>(src, dst, sigma, sv, tv, attn_b,
                                           cursC, btot, tmp, bbase);
    k_binB    <<<NBUCKET, 256, 0, stream>>>(tmp, bbase, colptr, recs);
    k_agg     <<<N_NODES / 4, 256, 0, stream>>>(colptr, recs, zh, out);
    k_bnstats <<<256, 256, 0, stream>>>(out, bns);
    k_bnapply <<<(N_NODES * 128) / (256 * 4), 256, 0, stream>>>(out, bns, gamma, beta);
}

// Round 7
// 210.303 us; speedup vs baseline: 1.1966x; 1.0719x over previous
//
#include <hip/hip_runtime.h>
#include <hip/hip_fp16.h>
#include <math.h>

#define N_NODES 50000
#define N_EDGES 800000
#define BIGV 1000000000.0f
#define NBLK_GEMM 3125  // 50000 / 16 nodes per block
#define CHUNK 1024      // edges per chunk (pass A granularity)
#define NCHUNK 782      // ceil(800000/1024)
#define NBUCKET 782     // dst>>6 in [0,781]
#define NB4 784         // bucket / chunk count padded to multiple of 4
#define BMAX 1280       // LDS record capacity per bucket (Poisson(1024)+8sigma)
#define NBLK_BN 512     // bnstats partial blocks

typedef _Float16 half8 __attribute__((ext_vector_type(8)));
typedef float floatx4 __attribute__((ext_vector_type(4)));

__device__ __forceinline__ float clampinf(float x) { return isinf(x) ? BIGV : x; }

// lgkm-only workgroup barrier: leaves global stores in flight.
__device__ __forceinline__ void barrier_lgkm_only() {
    __builtin_amdgcn_sched_barrier(0);
    asm volatile("s_waitcnt lgkmcnt(0)" ::: "memory");
    __builtin_amdgcn_s_barrier();
    __builtin_amdgcn_sched_barrier(0);
}

// ---------------------------------------------------------------------------
// k_prep: W pre-cast (fp16 W^T) + per-chunk bucket histogram (transposed).
// ---------------------------------------------------------------------------
__global__ __launch_bounds__(256) void k_prep(const float* __restrict__ W,
                                              __half* __restrict__ wt,
                                              const int* __restrict__ dst,
                                              int* __restrict__ countsT)
{
    __shared__ int hist[NB4];
    const int t = threadIdx.x;
    const int idx = blockIdx.x * 256 + t;
    if (idx < 16384) {
        int n = idx >> 7, k = idx & 127;
        wt[idx] = __float2half(W[k * 128 + n]);
    }
    for (int i = t; i < NB4; i += 256) hist[i] = 0;
    __syncthreads();
    const int base = blockIdx.x * CHUNK;
    for (int i = t; i < CHUNK; i += 256) {
        int e = base + i;
        if (e < N_EDGES) atomicAdd(&hist[dst[e] >> 6], 1);   // LDS atomic
    }
    __syncthreads();
    for (int i = t; i < NB4; i += 256)
        countsT[i * NB4 + blockIdx.x] = hist[i];             // transposed store
}

// ---------------------------------------------------------------------------
// k_off: one wave per bucket — exclusive prefix over the 782 chunks via
// 13-pass shfl_up wave-scan; writes cursC[chunk][bucket] + btot[bucket].
// ---------------------------------------------------------------------------
__global__ __launch_bounds__(256) void k_off(const int* __restrict__ countsT,
                                             int* __restrict__ cursC,
                                             int* __restrict__ btot)
{
    const int wv = (blockIdx.x << 2) + (threadIdx.x >> 6);   // bucket id
    const int l = threadIdx.x & 63;
    if (wv >= NBUCKET) {
        if (l == 0 && wv < NB4) btot[wv] = 0;
        return;
    }
    const int* row = countsT + (size_t)wv * NB4;
    int carry = 0;
    #pragma unroll
    for (int p = 0; p < 13; ++p) {                           // 13*64 = 832 >= 782
        const int c = p * 64 + l;
        const int v = (c < NCHUNK) ? row[c] : 0;
        int x = v;
        #pragma unroll
        for (int o = 1; o < 64; o <<= 1) {
            int u = __shfl_up(x, o);
            if (l >= o) x += u;
        }
        if (c < NCHUNK) cursC[(size_t)c * NB4 + wv] = carry + x - v;
        carry += __shfl(x, 63);
    }
    if (l == 0) btot[wv] = carry;
}

// ---------------------------------------------------------------------------
// K1: z = h @ W + b via MFMA f16, fp16 z out, fused per-node scores.
// ---------------------------------------------------------------------------
__global__ __launch_bounds__(256) void k_gemm(
    const float* __restrict__ h, const __half* __restrict__ wt,
    const float* __restrict__ bias, const float* __restrict__ attn_w,
    __half* __restrict__ zh, float* __restrict__ sv, float* __restrict__ tv)
{
    __shared__ _Float16 hA[16][136];
    __shared__ float spart[4][16], tpart[4][16];

    const int tid = threadIdx.x;
    const int lane = tid & 63;
    const int wv = tid >> 6;          // wave 0..3
    const int l16 = lane & 15;
    const int oct = lane >> 4;
    const int n0 = wv << 5;           // this wave's 32-col strip
    const int node0 = blockIdx.x << 4;

    // stage h tile as fp16 (512 float4; 32 float4 per row)
    {
        const float4* h4 = (const float4*)(h + (size_t)node0 * 128);
        for (int i = tid; i < 512; i += 256) {
            int r = i >> 5, c4 = i & 31;
            float4 v = h4[i];
            union { __half2 h2[2]; uint2 u; } pk;
            pk.h2[0] = __floats2half2_rn(v.x, v.y);
            pk.h2[1] = __floats2half2_rn(v.z, v.w);
            *(uint2*)&hA[r][c4 << 2] = pk.u;
        }
    }

    // B-fragments in registers
    half8 bfrag[4][2];
    #pragma unroll
    for (int kk = 0; kk < 4; ++kk)
        #pragma unroll
        for (int t = 0; t < 2; ++t)
            bfrag[kk][t] = *(const half8*)(wt + (size_t)(n0 + t * 16 + l16) * 128
                                              + kk * 32 + oct * 8);

    const float bv0 = bias[n0 + l16],         bv1 = bias[n0 + 16 + l16];
    const float ws0 = attn_w[n0 + l16],       ws1 = attn_w[n0 + 16 + l16];
    const float wd0 = attn_w[128 + n0 + l16], wd1 = attn_w[128 + n0 + 16 + l16];

    barrier_lgkm_only();   // staging visible; global loads stay in flight

    floatx4 acc0 = {0.f, 0.f, 0.f, 0.f};
    floatx4 acc1 = {0.f, 0.f, 0.f, 0.f};
    #pragma unroll
    for (int kk = 0; kk < 4; ++kk) {
        half8 a = *(const half8*)&hA[l16][(kk << 5) + (oct << 3)];
        acc0 = __builtin_amdgcn_mfma_f32_16x16x32_f16(a, bfrag[kk][0], acc0, 0, 0, 0);
        acc1 = __builtin_amdgcn_mfma_f32_16x16x32_f16(a, bfrag[kk][1], acc1, 0, 0, 0);
    }

    float s_acc[4], t_acc[4];
    #pragma unroll
    for (int r = 0; r < 4; ++r) {
        float z0 = clampinf(acc0[r] + bv0);
        float z1 = clampinf(acc1[r] + bv1);
        const int row = (oct << 2) + r;
        zh[(size_t)(node0 + row) * 128 + n0 + l16]      = __float2half(z0);
        zh[(size_t)(node0 + row) * 128 + n0 + 16 + l16] = __float2half(z1);
        s_acc[r] = z0 * ws0 + z1 * ws1;
        t_acc[r] = z0 * wd0 + z1 * wd1;
    }
    #pragma unroll
    for (int r = 0; r < 4; ++r) {
        #pragma unroll
        for (int o = 1; o < 16; o <<= 1) {
            s_acc[r] += __shfl_xor(s_acc[r], o);
            t_acc[r] += __shfl_xor(t_acc[r], o);
        }
    }
    if (l16 == 0) {
        #pragma unroll
        for (int r = 0; r < 4; ++r) {
            spart[wv][(oct << 2) + r] = s_acc[r];
            tpart[wv][(oct << 2) + r] = t_acc[r];
        }
    }
    barrier_lgkm_only();
    if (tid < 16) {
        sv[node0 + tid] = spart[0][tid] + spart[1][tid] + spart[2][tid] + spart[3][tid];
        tv[node0 + tid] = tpart[0][tid] + tpart[1][tid] + tpart[2][tid] + tpart[3][tid];
    }
}

// ---------------------------------------------------------------------------
// PASS A (k_scat): per 1024-edge chunk: cheap cursor setup (coalesced cursC
// row + redundant LDS scan of btot), then compute final edge payload with
// coalesced reads and scatter 16B records into bucket slices. Publishes bbase.
// ---------------------------------------------------------------------------
__global__ __launch_bounds__(256) void k_scat(
    const int* __restrict__ src, const int* __restrict__ dst,
    const float* __restrict__ sigma,
    const float* __restrict__ sv, const float* __restrict__ tv,
    const float* __restrict__ attn_b,
    const int* __restrict__ cursC, const int* __restrict__ btot,
    float4* __restrict__ tmp, int* __restrict__ bbase_g)
{
    __shared__ int cur[NB4];
    __shared__ int bb[NB4];
    __shared__ int tsc[256];
    const int t = threadIdx.x;
    const int self = blockIdx.x;

    for (int i = t; i < NB4; i += 256) cur[i] = cursC[(size_t)self * NB4 + i];

    uint4 bt = {0u, 0u, 0u, 0u};
    int tsum = 0;
    if (t < 196) {
        bt = ((const uint4*)btot)[t];
        tsum = (int)(bt.x + bt.y + bt.z + bt.w);
    }
    tsc[t] = tsum;
    __syncthreads();
    for (int off = 1; off < 256; off <<= 1) {    // inclusive block scan
        int u = (t >= off) ? tsc[t - off] : 0;
        __syncthreads();
        tsc[t] += u;
        __syncthreads();
    }
    if (t < 196) {
        const int v0 = tsc[t] - tsum;            // exclusive
        bb[4*t+0] = v0;
        bb[4*t+1] = v0 + (int)bt.x;
        bb[4*t+2] = v0 + (int)bt.x + (int)bt.y;
        bb[4*t+3] = v0 + (int)bt.x + (int)bt.y + (int)bt.z;
    }
    __syncthreads();
    for (int i = t; i < NB4; i += 256) cur[i] += bb[i];
    if (self == 0)
        for (int i = t; i < NB4; i += 256) bbase_g[i] = bb[i];
    __syncthreads();

    const float ab = attn_b[0];
    const int base = self * CHUNK;
    for (int i = t; i < CHUNK; i += 256) {
        int e = base + i;
        if (e < N_EDGES) {
            int s = src[e];
            int d = dst[e];
            float a = sv[s] + tv[d] + ab;
            a = clampinf(a);
            float ev = a > 0.f ? a : 0.01f * a;  // leaky relu
            int pos = atomicAdd(&cur[d >> 6], 1);  // LDS atomic
            float4 rec;
            rec.x = __int_as_float(s);
            rec.y = sigma[e];
            rec.z = ev;
            rec.w = __int_as_float(d);
            tmp[pos] = rec;
        }
    }
}

// ---------------------------------------------------------------------------
// k_bagg: FUSED binB + agg. One block (8 waves) per bucket (~1024 edges,
// 64 nodes). Stage + bin the bucket's records in LDS (20 KB), then each wave
// processes 8 nodes: wave softmax + z-row gather-accumulate, write out.
// Eliminates the recs round-trip (25.6 MB) + colptr + one dispatch.
// Overflow (bucket > BMAX, ~8-sigma event): spill to global ovf, correct path.
// ---------------------------------------------------------------------------
__global__ __launch_bounds__(512) void k_bagg(
    const float4* __restrict__ tmp, const int* __restrict__ bbase_g,
    const __half* __restrict__ zh, float4* __restrict__ ovf,
    float* __restrict__ out)
{
    __shared__ float4 lrec[BMAX];
    __shared__ int hist[64];
    __shared__ int segs[65];
    __shared__ int cur[64];
    const int t = threadIdx.x;
    const int b = blockIdx.x;
    const int s0 = bbase_g[b];
    const int n = bbase_g[b + 1] - s0;   // bbase_g[782] == N_EDGES (padding)

    if (t < 64) hist[t] = 0;
    __syncthreads();
    // phase 1: histogram of node-within-bucket
    const float* tw = (const float*)tmp;
    for (int i = t; i < n; i += 512) {
        int d = __float_as_int(tw[4 * (size_t)(s0 + i) + 3]);
        atomicAdd(&hist[d & 63], 1);                 // LDS atomic
    }
    __syncthreads();
    // wave 0: exclusive scan of the 64 bins
    if (t < 64) {
        const int hv = hist[t];
        int x = hv;
        #pragma unroll
        for (int o = 1; o < 64; o <<= 1) {
            int u = __shfl_up(x, o);
            if (t >= o) x += u;
        }
        segs[t] = x - hv;
        cur[t]  = x - hv;
        if (t == 63) segs[64] = x;
    }
    __syncthreads();
    // phase 2: place records binned into LDS (global spill if > BMAX)
    for (int i = t; i < n; i += 512) {
        float4 rec = tmp[s0 + i];
        int d = __float_as_int(rec.w);
        int pos = atomicAdd(&cur[d & 63], 1);        // bucket-relative slot
        if (pos < BMAX) lrec[pos] = rec;
        else            ovf[s0 + pos] = rec;
    }
    __syncthreads();

    // phase 3: aggregation — wave wv handles nodes wv, wv+8, ...
    const int lane = t & 63;
    const int wv = t >> 6;
    const int grp = lane >> 4;
    const int l16 = lane & 15;

    for (int j = wv; j < 64; j += 8) {
        const int node = (b << 6) + j;
        if (node >= N_NODES) continue;
        const int beg = segs[j];
        const int deg = segs[j + 1] - beg;
        float acc[8] = {0.f, 0.f, 0.f, 0.f, 0.f, 0.f, 0.f, 0.f};

        if (deg > 0) {
            if (deg <= 64) {
                int sidx = 0; float sig = 0.f, e = -INFINITY;
                if (lane < deg) {
                    const int off = beg + lane;
                    float4 r = (off < BMAX) ? lrec[off] : ovf[s0 + off];
                    sidx = __float_as_int(r.x); sig = r.y; e = r.z;
                }
                float m = e;
                for (int o = 32; o; o >>= 1) m = fmaxf(m, __shfl_xor(m, o));
                float p = (lane < deg) ? __expf(e - m) : 0.f;
                float dn = p, bs = sig;
                for (int o = 32; o; o >>= 1) {
                    dn += __shfl_xor(dn, o);
                    bs += __shfl_xor(bs, o);
                }
                const float coef = p * sig * (1.0f / dn) / (bs + 1e-6f);
                for (int c = 0; c < deg; c += 4) {
                    const int jj = c + grp;
                    const int js = (jj < deg) ? jj : 0;
                    float cf = __shfl(coef, js);       // uniform: all lanes
                    int sj = __shfl(sidx, js);
                    if (jj < deg) {
                        uint4 raw = *(const uint4*)(zh + ((size_t)sj << 7) + (l16 << 3));
                        const __half2* hp = (const __half2*)&raw;
                        #pragma unroll
                        for (int k = 0; k < 4; ++k) {
                            float2 f = __half22float2(hp[k]);
                            acc[2*k]   = fmaf(cf, f.x, acc[2*k]);
                            acc[2*k+1] = fmaf(cf, f.y, acc[2*k+1]);
                        }
                    }
                }
            } else {
                // generic path (deg > 64 — absent for this input, kept correct)
                float m = -INFINITY;
                for (int i = lane; i < deg; i += 64) {
                    const int off = beg + i;
                    float4 r = (off < BMAX) ? lrec[off] : ovf[s0 + off];
                    m = fmaxf(m, r.z);
                }
                for (int o = 32; o; o >>= 1) m = fmaxf(m, __shfl_xor(m, o));
                float dn = 0.f, bs = 0.f;
                for (int i = lane; i < deg; i += 64) {
                    const int off = beg + i;
                    float4 r = (off < BMAX) ? lrec[off] : ovf[s0 + off];
                    dn += __expf(r.z - m); bs += r.y;
                }
                for (int o = 32; o; o >>= 1) {
                    dn += __shfl_xor(dn, o);
                    bs += __shfl_xor(bs, o);
                }
                const float scale = (1.0f / dn) / (bs + 1e-6f);
                for (int c = 0; c < deg; c += 64) {
                    int i = c + lane;
                    int sidx = 0; float coef = 0.f;
                    if (i < deg) {
                        const int off = beg + i;
                        float4 r = (off < BMAX) ? lrec[off] : ovf[s0 + off];
                        sidx = __float_as_int(r.x);
                        coef = __expf(r.z - m) * r.y * scale;
                    }
                    const int cnt2 = min(64, deg - c);
                    for (int jj = 0; jj < cnt2; jj += 4) {
                        const int j4 = jj + grp;
                        const int js = (j4 < cnt2) ? j4 : 0;
                        float cf = __shfl(coef, js);
                        int sj = __shfl(sidx, js);
                        if (j4 < cnt2) {
                            uint4 raw = *(const uint4*)(zh + ((size_t)sj << 7) + (l16 << 3));
                            const __half2* hp = (const __half2*)&raw;
                            #pragma unroll
                            for (int k = 0; k < 4; ++k) {
                                float2 f = __half22float2(hp[k]);
                                acc[2*k]   = fmaf(cf, f.x, acc[2*k]);
                                acc[2*k+1] = fmaf(cf, f.y, acc[2*k+1]);
                            }
                        }
                    }
                }
            }
        }
        // combine 4 groups: feature 8*l16+k lives in lanes {l16,+16,+32,+48}
        #pragma unroll
        for (int k = 0; k < 8; ++k) {
            acc[k] += __shfl_xor(acc[k], 16);
            acc[k] += __shfl_xor(acc[k], 32);
        }
        if (grp == 0) {
            float4 o0, o1;
            o0.x = clampinf(acc[0]); o0.y = clampinf(acc[1]);
            o0.z = clampinf(acc[2]); o0.w = clampinf(acc[3]);
            o1.x = clampinf(acc[4]); o1.y = clampinf(acc[5]);
            o1.z = clampinf(acc[6]); o1.w = clampinf(acc[7]);
            float4* op = (float4*)(out + (size_t)node * 128 + (l16 << 3));
            op[0] = o0; op[1] = o1;
        }
    }
}

// ---------------------------------------------------------------------------
// BN stats WITHOUT global atomics (R0-R3 lesson: same-line global RMW
// serializes at the coherence point). Each block writes non-atomic partials
// [block][256]; k_bnred (1 block, 1024 thr) reduces them to sums.
// ---------------------------------------------------------------------------
__global__ __launch_bounds__(256) void k_bnstats(const float* __restrict__ hnew,
                                                 float* __restrict__ partials)
{
    const int tid = threadIdx.x;
    const int f4 = (tid & 31) << 2;
    const int rgrp = tid >> 5;           // 0..7
    float4 s = {0.f, 0.f, 0.f, 0.f}, q = {0.f, 0.f, 0.f, 0.f};
    for (int node = blockIdx.x * 8 + rgrp; node < N_NODES; node += NBLK_BN * 8) {
        float4 v = *(const float4*)(hnew + (size_t)node * 128 + f4);
        s.x += v.x; s.y += v.y; s.z += v.z; s.w += v.w;
        q.x += v.x * v.x; q.y += v.y * v.y; q.z += v.z * v.z; q.w += v.w * v.w;
    }
    __shared__ float4 ls[256], lq[256];
    ls[tid] = s; lq[tid] = q;
    __syncthreads();
    for (int off = 128; off >= 32; off >>= 1) {
        if (tid < off) {
            float4 a = ls[tid + off], b = lq[tid + off];
            ls[tid].x += a.x; ls[tid].y += a.y; ls[tid].z += a.z; ls[tid].w += a.w;
            lq[tid].x += b.x; lq[tid].y += b.y; lq[tid].z += b.z; lq[tid].w += b.w;
        }
        __syncthreads();
    }
    if (tid < 32) {
        float* p = partials + (size_t)blockIdx.x * 256;
        *(float4*)(p + f4)       = ls[tid];
        *(float4*)(p + 128 + f4) = lq[tid];
    }
}

__global__ __launch_bounds__(1024) void k_bnred(const float* __restrict__ partials,
                                                float* __restrict__ sums)
{
    __shared__ float red[4][256];
    const int t = threadIdx.x;
    const int f = t & 255;
    const int part = t >> 8;             // 0..3, each covers 128 blocks
    float s = 0.f;
    #pragma unroll 8
    for (int b = part * (NBLK_BN / 4); b < (part + 1) * (NBLK_BN / 4); ++b)
        s += partials[(size_t)b * 256 + f];
    red[part][f] = s;
    __syncthreads();
    if (part == 0)
        sums[f] = red[0][f] + red[1][f] + red[2][f] + red[3][f];
}

// ---------------------------------------------------------------------------
// BN apply + ELU: float4-vectorized; per-feature scale/shift in LDS.
// ---------------------------------------------------------------------------
__global__ __launch_bounds__(256) void k_bnapply(float* __restrict__ io,
                                                 const float* __restrict__ sums,
                                                 const float* __restrict__ gamma,
                                                 const float* __restrict__ beta)
{
    __shared__ float sc[128], sh[128];
    const int tid = threadIdx.x;
    if (tid < 128) {
        const float invn = 1.0f / (float)N_NODES;
        float mu = sums[tid] * invn;
        float var = fmaxf(sums[128 + tid] * invn - mu * mu, 0.f);
        float g = gamma[tid] * rsqrtf(var + 1e-5f);
        sc[tid] = g;
        sh[tid] = beta[tid] - mu * g;
    }
    __syncthreads();
    const size_t idx = (size_t)blockIdx.x * 256 + tid;   // float4 index
    const int f4 = ((int)idx & 31) << 2;
    float4 x = ((const float4*)io)[idx];
    float y0 = x.x * sc[f4 + 0] + sh[f4 + 0];
    float y1 = x.y * sc[f4 + 1] + sh[f4 + 1];
    float y2 = x.z * sc[f4 + 2] + sh[f4 + 2];
    float y3 = x.w * sc[f4 + 3] + sh[f4 + 3];
    float4 o;
    o.x = y0 > 0.f ? y0 : expm1f(y0);
    o.y = y1 > 0.f ? y1 : expm1f(y1);
    o.z = y2 > 0.f ? y2 : expm1f(y2);
    o.w = y3 > 0.f ? y3 : expm1f(y3);
    ((float4*)io)[idx] = o;
}

// ---------------------------------------------------------------------------
extern "C" void kernel_launch(void* const* d_in, const int* in_sizes, int n_in,
                              void* d_out, int out_size, void* d_ws, size_t ws_size,
                              hipStream_t stream)
{
    const float* h      = (const float*)d_in[0];
    const int*   src    = (const int*)  d_in[1];
    const int*   dst    = (const int*)  d_in[2];
    const float* sigma  = (const float*)d_in[3];
    const float* fc_w   = (const float*)d_in[4];
    const float* fc_b   = (const float*)d_in[5];
    const float* attn_w = (const float*)d_in[6];
    const float* attn_b = (const float*)d_in[7];
    const float* gamma  = (const float*)d_in[8];
    const float* beta   = (const float*)d_in[9];
    float* out = (float*)d_out;

    // workspace layout (~45 MB)
    float4* tmp    = (float4*)d_ws;                         // 800000 x 16B
    float4* ovf    = tmp + N_EDGES;                         // 800000 x 16B (spill)
    __half* zh     = (__half*)(ovf + N_EDGES);              // 50000*128 fp16
    float*  sv     = (float*)(zh + (size_t)N_NODES * 128);  // 50000
    float*  tv     = sv + N_NODES;                          // 50000
    float*  bns    = tv + N_NODES;                          // 256
    float*  parts  = bns + 256;                             // 512*256
    __half* wt     = (__half*)(parts + NBLK_BN * 256);      // 128*128 fp16 (W^T)
    int*    countsT= (int*)(wt + 16384);                    // 784*784
    int*    cursC  = countsT + NB4 * NB4;                   // 784*784
    int*    btot   = cursC + NB4 * NB4;                     // 784
    int*    bbase  = btot + NB4;                            // 784

    k_prep    <<<NCHUNK, 256, 0, stream>>>(fc_w, wt, dst, countsT);
    k_off     <<<196, 256, 0, stream>>>(countsT, cursC, btot);
    k_gemm    <<<NBLK_GEMM, 256, 0, stream>>>(h, wt, fc_b, attn_w, zh, sv, tv);
    k_scat    <<<NCHUNK, 256, 0, stream>>>(src, dst, sigma, sv, tv, attn_b,
                                           cursC, btot, tmp, bbase);
    k_bagg    <<<NBUCKET, 512, 0, stream>>>(tmp, bbase, zh, ovf, out);
    k_bnstats <<<NBLK_BN, 256, 0, stream>>>(out, parts);
    k_bnred   <<<1, 1024, 0, stream>>>(parts, bns);
    k_bnapply <<<(N_NODES * 128) / (256 * 4), 256, 0, stream>>>(out, bns, gamma, beta);
}